// Round 1
// baseline (1540.757 us; speedup 1.0000x reference)
//
#include <hip/hip_runtime.h>

#define NU 100000
#define NI 50000
#define NN 150000   // NU + NI
#define D  64

// ---------------- wave helpers ----------------
__device__ __forceinline__ float wave_reduce_add(float v) {
    #pragma unroll
    for (int m = 32; m >= 1; m >>= 1) v += __shfl_xor(v, m, 64);
    return v;
}

// ---------------- degree + count (per edge) ----------------
__global__ void k_deg_count(const int* __restrict__ src, const int* __restrict__ dst,
                            const float* __restrict__ ew,
                            float* __restrict__ deg, int* __restrict__ counts, int E) {
    int e = blockIdx.x * blockDim.x + threadIdx.x;
    if (e >= E) return;
    int d = dst[e];
    atomicAdd(&deg[d], ew[e]);
    atomicAdd(&counts[d], 1);
    (void)src;
}

// dinv = rsqrt(deg + 1)   (self-loop weight 1.0 folded in; deg+1 > 0 always)
__global__ void k_dinv(const float* __restrict__ deg, float* __restrict__ dinv, int n) {
    int i = blockIdx.x * blockDim.x + threadIdx.x;
    if (i < n) {
        float dg = deg[i] + 1.0f;
        dinv[i] = rsqrtf(dg);
    }
}

// ---------------- block-wise exclusive scan of counts ----------------
__global__ void k_scan1(const int* __restrict__ counts, int* __restrict__ excl,
                        int* __restrict__ partials, int n) {
    __shared__ int tmp[256];
    int t = threadIdx.x;
    int i = blockIdx.x * 256 + t;
    int v = (i < n) ? counts[i] : 0;
    tmp[t] = v;
    __syncthreads();
    #pragma unroll
    for (int off = 1; off < 256; off <<= 1) {
        int t2 = (t >= off) ? tmp[t - off] : 0;
        __syncthreads();
        tmp[t] += t2;
        __syncthreads();
    }
    if (i < n) excl[i] = tmp[t] - v;           // exclusive within block
    if (t == 255) partials[blockIdx.x] = tmp[t]; // block total
}

__global__ void k_scan2(int* __restrict__ partials, int m) {
    __shared__ int tmp[1024];
    int t = threadIdx.x;
    int v = (t < m) ? partials[t] : 0;
    tmp[t] = v;
    __syncthreads();
    #pragma unroll
    for (int off = 1; off < 1024; off <<= 1) {
        int t2 = (t >= off) ? tmp[t - off] : 0;
        __syncthreads();
        tmp[t] += t2;
        __syncthreads();
    }
    if (t < m) partials[t] = tmp[t] - v;       // exclusive block offsets
}

__global__ void k_scan3(int* __restrict__ offs, const int* __restrict__ partials,
                        int* __restrict__ cursor, int n) {
    int i = blockIdx.x * blockDim.x + threadIdx.x;
    if (i >= n) return;
    int o = offs[i] + partials[i >> 8];
    offs[i] = o;
    cursor[i] = o;
}

// ---------------- CSR fill: slot per edge, precompute norm ----------------
__global__ void k_fill(const int* __restrict__ src, const int* __restrict__ dst,
                       const float* __restrict__ ew, const float* __restrict__ dinv,
                       int* __restrict__ cursor, int* __restrict__ eidx,
                       float* __restrict__ enorm, int E) {
    int e = blockIdx.x * blockDim.x + threadIdx.x;
    if (e >= E) return;
    int s = src[e], d = dst[e];
    float nrm = dinv[s] * ew[e] * dinv[d];
    int slot = atomicAdd(&cursor[d], 1);
    eidx[slot] = s;
    enorm[slot] = nrm;
}

// ---------------- small GEMM: out[n] = row(n) @ W   (W 64x64 in LDS) ----------------
__global__ void k_gemm(const float* __restrict__ h, const float* __restrict__ U,
                       const float* __restrict__ I, const float* __restrict__ W,
                       float* __restrict__ out) {
    __shared__ float Ws[64 * 64];
    for (int i = threadIdx.x; i < 64 * 64; i += blockDim.x) Ws[i] = W[i];
    __syncthreads();
    int lane = threadIdx.x & 63;
    int wpb = blockDim.x >> 6;
    int wid = blockIdx.x * wpb + (threadIdx.x >> 6);
    int tw = gridDim.x * wpb;
    for (int n = wid; n < NN; n += tw) {
        float xv;
        if (h) xv = h[n * D + lane];
        else   xv = (n < NU) ? U[n * D + lane] : I[(n - NU) * D + lane];
        float acc = 0.f;
        #pragma unroll
        for (int k = 0; k < 64; ++k)
            acc += __shfl(xv, k, 64) * Ws[k * 64 + lane];
        out[n * D + lane] = acc;
    }
}

// ---------------- conv gather: one wave per dst node ----------------
__global__ void k_conv(const float* __restrict__ hw, const int* __restrict__ offs,
                       const int* __restrict__ counts, const int* __restrict__ eidx,
                       const float* __restrict__ enorm, const float* __restrict__ dinv,
                       float* __restrict__ out) {
    int lane = threadIdx.x & 63;
    int n = blockIdx.x * (blockDim.x >> 6) + (threadIdx.x >> 6);
    if (n >= NN) return;
    float di = dinv[n];
    float a = di * di * hw[n * D + lane];   // self-loop contribution
    int st = offs[n], cnt = counts[n];
    for (int j = st; j < st + cnt; ++j) {
        int s = eidx[j];
        float w = enorm[j];
        a += w * hw[s * D + lane];
    }
    out[n * D + lane] = a;
}

// ---------------- bias + layernorm + relu + residual ----------------
__global__ void k_pw(const float* __restrict__ acc, const float* __restrict__ b,
                     const float* __restrict__ g, const float* __restrict__ be,
                     const float* __restrict__ resid, const float* __restrict__ U,
                     const float* __restrict__ I, float* __restrict__ out) {
    int lane = threadIdx.x & 63;
    int n = blockIdx.x * (blockDim.x >> 6) + (threadIdx.x >> 6);
    if (n >= NN) return;
    float v = acc[n * D + lane] + b[lane];
    float m = wave_reduce_add(v) * (1.0f / 64.0f);
    float dv = v - m;
    float var = wave_reduce_add(dv * dv) * (1.0f / 64.0f);
    float y = dv * rsqrtf(var + 1e-5f) * g[lane] + be[lane];
    y = fmaxf(y, 0.0f);
    float r = resid ? resid[n * D + lane]
                    : ((n < NU) ? U[n * D + lane] : I[(n - NU) * D + lane]);
    out[n * D + lane] = y + r;
}

// ---------------- fused projection + scoring ----------------
__global__ void k_score(const float* __restrict__ h2, const int* __restrict__ users,
                        const int* __restrict__ items, const float* __restrict__ Wp,
                        const float* __restrict__ bp, const float* __restrict__ bu,
                        const float* __restrict__ bi, const float* __restrict__ mu,
                        float* __restrict__ out, int B) {
    __shared__ float Ws[64 * 64];
    for (int i = threadIdx.x; i < 64 * 64; i += blockDim.x) Ws[i] = Wp[i];
    __syncthreads();
    int lane = threadIdx.x & 63;
    int wpb = blockDim.x >> 6;
    int wid = blockIdx.x * wpb + (threadIdx.x >> 6);
    int tw = gridDim.x * wpb;
    for (int p = wid; p < B; p += tw) {
        int u = users[p];
        int it = items[p];
        float hu = h2[u * D + lane];
        float hi = h2[(NU + it) * D + lane];
        float pu = bp[lane], pi = bp[lane];
        #pragma unroll
        for (int k = 0; k < 64; ++k) {
            float wv = Ws[k * 64 + lane];
            pu += __shfl(hu, k, 64) * wv;
            pi += __shfl(hi, k, 64) * wv;
        }
        float s = wave_reduce_add(pu * pi);
        if (lane == 0) {
            s += bu[u] + bi[it] + mu[0];
            s = fminf(fmaxf(s, 1.0f), 5.0f);
            out[p] = s;
        }
    }
}

extern "C" void kernel_launch(void* const* d_in, const int* in_sizes, int n_in,
                              void* d_out, int out_size, void* d_ws, size_t ws_size,
                              hipStream_t stream) {
    const int*   users = (const int*)d_in[0];
    const int*   items = (const int*)d_in[1];
    const int*   ei2   = (const int*)d_in[2];
    const float* ew    = (const float*)d_in[3];
    const float* U     = (const float*)d_in[4];
    const float* I     = (const float*)d_in[5];
    const float* W0    = (const float*)d_in[6];
    const float* b0    = (const float*)d_in[7];
    const float* g0    = (const float*)d_in[8];
    const float* be0   = (const float*)d_in[9];
    const float* W1    = (const float*)d_in[10];
    const float* b1    = (const float*)d_in[11];
    const float* g1    = (const float*)d_in[12];
    const float* be1   = (const float*)d_in[13];
    const float* Wp    = (const float*)d_in[14];
    const float* bp    = (const float*)d_in[15];
    const float* bu    = (const float*)d_in[16];
    const float* bi    = (const float*)d_in[17];
    const float* mu    = (const float*)d_in[18];

    int B = in_sizes[0];
    int E = in_sizes[2] / 2;
    const int* srcp = ei2;
    const int* dstp = ei2 + E;

    // workspace carve-up (256B aligned)
    char* p = (char*)d_ws;
    auto alloc = [&](size_t bytes) -> char* {
        char* r = p;
        p += (bytes + 255) & ~(size_t)255;
        return r;
    };
    float* deg    = (float*)alloc((size_t)NN * 4);
    int*   counts = (int*)  alloc((size_t)NN * 4);
    float* dinv   = (float*)alloc((size_t)NN * 4);
    int*   offs   = (int*)  alloc((size_t)NN * 4);
    int*   cursor = (int*)  alloc((size_t)NN * 4);
    int*   parts  = (int*)  alloc(1024 * 4);
    int*   eidx   = (int*)  alloc((size_t)E * 4);
    float* enorm  = (float*)alloc((size_t)E * 4);
    float* hw     = (float*)alloc((size_t)NN * D * 4);
    float* acc    = (float*)alloc((size_t)NN * D * 4);
    float* h1     = (float*)alloc((size_t)NN * D * 4);

    hipMemsetAsync(deg, 0, (size_t)NN * 4, stream);
    hipMemsetAsync(counts, 0, (size_t)NN * 4, stream);

    int gE = (E + 255) / 256;
    int gN = (NN + 255) / 256;      // 586 blocks, fits in 1024-wide scan2
    int gW = (NN + 3) / 4;          // 4 waves (nodes) per 256-thread block

    k_deg_count<<<gE, 256, 0, stream>>>(srcp, dstp, ew, deg, counts, E);
    k_dinv<<<gN, 256, 0, stream>>>(deg, dinv, NN);
    k_scan1<<<gN, 256, 0, stream>>>(counts, offs, parts, NN);
    k_scan2<<<1, 1024, 0, stream>>>(parts, gN);
    k_scan3<<<gN, 256, 0, stream>>>(offs, parts, cursor, NN);
    k_fill<<<gE, 256, 0, stream>>>(srcp, dstp, ew, dinv, cursor, eidx, enorm, E);

    // layer 1
    k_gemm<<<2048, 256, 0, stream>>>(nullptr, U, I, W0, hw);
    k_conv<<<gW, 256, 0, stream>>>(hw, offs, counts, eidx, enorm, dinv, acc);
    k_pw<<<gW, 256, 0, stream>>>(acc, b0, g0, be0, nullptr, U, I, h1);

    // layer 2
    k_gemm<<<2048, 256, 0, stream>>>(h1, U, I, W1, hw);
    k_conv<<<gW, 256, 0, stream>>>(hw, offs, counts, eidx, enorm, dinv, acc);
    k_pw<<<gW, 256, 0, stream>>>(acc, b1, g1, be1, h1, U, I, hw);  // h2 -> hw

    // fused projection + scoring
    k_score<<<512, 256, 0, stream>>>(hw, users, items, Wp, bp, bu, bi, mu,
                                     (float*)d_out, B);
}

// Round 2
// 1355.730 us; speedup vs baseline: 1.1365x; 1.1365x over previous
//
#include <hip/hip_runtime.h>

#define NU 100000
#define NI 50000
#define NN 150000   // NU + NI
#define D  64

// ---------------- wave helpers ----------------
__device__ __forceinline__ float wave_reduce_add(float v) {
    #pragma unroll
    for (int m = 32; m >= 1; m >>= 1) v += __shfl_xor(v, m, 64);
    return v;
}

// ---------------- per-edge: degree (weighted) + count ----------------
__global__ void k_count(const int* __restrict__ dst, const float* __restrict__ ew,
                        float* __restrict__ deg, int* __restrict__ counts, int E) {
    int e = blockIdx.x * blockDim.x + threadIdx.x;
    if (e >= E) return;
    int d = dst[e];
    atomicAdd(&deg[d], ew[e]);
    atomicAdd(&counts[d], 1);
}

// dinv = rsqrt(deg + 1)   (self-loop weight 1.0 folded in; deg+1 > 0 always)
__global__ void k_dinv(const float* __restrict__ deg, float* __restrict__ dinv, int n) {
    int i = blockIdx.x * blockDim.x + threadIdx.x;
    if (i < n) dinv[i] = rsqrtf(deg[i] + 1.0f);
}

// ---------------- block-wise exclusive scan of counts ----------------
__global__ void k_scan1(const int* __restrict__ counts, int* __restrict__ excl,
                        int* __restrict__ partials, int n) {
    __shared__ int tmp[256];
    int t = threadIdx.x;
    int i = blockIdx.x * 256 + t;
    int v = (i < n) ? counts[i] : 0;
    tmp[t] = v;
    __syncthreads();
    #pragma unroll
    for (int off = 1; off < 256; off <<= 1) {
        int t2 = (t >= off) ? tmp[t - off] : 0;
        __syncthreads();
        tmp[t] += t2;
        __syncthreads();
    }
    if (i < n) excl[i] = tmp[t] - v;
    if (t == 255) partials[blockIdx.x] = tmp[t];
}

__global__ void k_scan2(int* __restrict__ partials, int m) {
    __shared__ int tmp[1024];
    int t = threadIdx.x;
    int v = (t < m) ? partials[t] : 0;
    tmp[t] = v;
    __syncthreads();
    #pragma unroll
    for (int off = 1; off < 1024; off <<= 1) {
        int t2 = (t >= off) ? tmp[t - off] : 0;
        __syncthreads();
        tmp[t] += t2;
        __syncthreads();
    }
    if (t < m) partials[t] = tmp[t] - v;
}

__global__ void k_scan3(int* __restrict__ offs, const int* __restrict__ partials,
                        int* __restrict__ cursor, int n, int E) {
    int i = blockIdx.x * blockDim.x + threadIdx.x;
    if (i >= n) return;
    int o = offs[i] + partials[i >> 8];
    offs[i] = o;
    cursor[i] = o;
    if (i == 0) offs[n] = E;   // sentinel so conv can use offs[n+1]-offs[n]
}

// ---------------- CSR fill: one packed 8B record per edge ----------------
__global__ void k_fill(const int* __restrict__ src, const int* __restrict__ dst,
                       const float* __restrict__ ew,
                       int* __restrict__ cursor, int2* __restrict__ recs, int E) {
    int e = blockIdx.x * blockDim.x + threadIdx.x;
    if (e >= E) return;
    int s = src[e], d = dst[e];
    int slot = atomicAdd(&cursor[d], 1);
    recs[slot] = make_int2(s, __float_as_int(ew[e]));
}

// ---------------- small GEMM + dinv row-scale: out[n] = dinv[n] * (row(n) @ W) --
__global__ void k_gemm(const float* __restrict__ h, const float* __restrict__ U,
                       const float* __restrict__ I, const float* __restrict__ W,
                       const float* __restrict__ dinv, float* __restrict__ out) {
    __shared__ float Ws[64 * 64];
    for (int i = threadIdx.x; i < 64 * 64; i += blockDim.x) Ws[i] = W[i];
    __syncthreads();
    int lane = threadIdx.x & 63;
    int wpb = blockDim.x >> 6;
    int wid = blockIdx.x * wpb + (threadIdx.x >> 6);
    int tw = gridDim.x * wpb;
    for (int n = wid; n < NN; n += tw) {
        float xv;
        if (h) xv = h[n * D + lane];
        else   xv = (n < NU) ? U[n * D + lane] : I[(n - NU) * D + lane];
        float acc = 0.f;
        #pragma unroll
        for (int k = 0; k < 64; ++k)
            acc += __shfl(xv, k, 64) * Ws[k * 64 + lane];
        out[n * D + lane] = acc * dinv[n];
    }
}

// ---------------- fused conv gather + bias + LN + ReLU + residual -------------
// hw2 is pre-scaled by dinv[src]; per dst:  a = dinv[d]*(hw2[d] + sum ew*hw2[s]) + b
__global__ __launch_bounds__(256) void k_conv_pw(
        const float* __restrict__ hw2, const int* __restrict__ offs,
        const int2* __restrict__ recs, const float* __restrict__ dinv,
        const float* __restrict__ b, const float* __restrict__ g,
        const float* __restrict__ be,
        const float* __restrict__ resid, const float* __restrict__ U,
        const float* __restrict__ I, float* __restrict__ out) {
    int lane = threadIdx.x & 63;
    int n = blockIdx.x * (blockDim.x >> 6) + (threadIdx.x >> 6);
    if (n >= NN) return;
    int st = offs[n], en = offs[n + 1];
    float a = hw2[(size_t)n * D + lane];          // self-loop term
    for (int j0 = st; j0 < en; j0 += 64) {
        int jn = en - j0; if (jn > 64) jn = 64;
        // coalesced batch-load of up to 64 edge records, then broadcast
        int2 rv = make_int2(0, 0);
        if (j0 + lane < en) rv = recs[j0 + lane];
        for (int j = 0; j < jn; ++j) {
            int   s = __shfl(rv.x, j, 64);
            float w = __int_as_float(__shfl(rv.y, j, 64));
            a += w * hw2[(size_t)s * D + lane];   // independent gathers, deep in flight
        }
    }
    float v = a * dinv[n] + b[lane];
    // layernorm over the 64 features (one wave)
    float m = wave_reduce_add(v) * (1.0f / 64.0f);
    float dv = v - m;
    float var = wave_reduce_add(dv * dv) * (1.0f / 64.0f);
    float y = dv * rsqrtf(var + 1e-5f) * g[lane] + be[lane];
    y = fmaxf(y, 0.0f);
    float r = resid ? resid[(size_t)n * D + lane]
                    : ((n < NU) ? U[(size_t)n * D + lane]
                                : I[(size_t)(n - NU) * D + lane]);
    out[(size_t)n * D + lane] = y + r;
}

// ---------------- fused projection + scoring ----------------
__global__ void k_score(const float* __restrict__ h2, const int* __restrict__ users,
                        const int* __restrict__ items, const float* __restrict__ Wp,
                        const float* __restrict__ bp, const float* __restrict__ bu,
                        const float* __restrict__ bi, const float* __restrict__ mu,
                        float* __restrict__ out, int B) {
    __shared__ float Ws[64 * 64];
    for (int i = threadIdx.x; i < 64 * 64; i += blockDim.x) Ws[i] = Wp[i];
    __syncthreads();
    int lane = threadIdx.x & 63;
    int wpb = blockDim.x >> 6;
    int wid = blockIdx.x * wpb + (threadIdx.x >> 6);
    int tw = gridDim.x * wpb;
    for (int p = wid; p < B; p += tw) {
        int u = users[p];
        int it = items[p];
        float hu = h2[(size_t)u * D + lane];
        float hi = h2[(size_t)(NU + it) * D + lane];
        float pu = bp[lane], pi = bp[lane];
        #pragma unroll
        for (int k = 0; k < 64; ++k) {
            float wv = Ws[k * 64 + lane];
            pu += __shfl(hu, k, 64) * wv;
            pi += __shfl(hi, k, 64) * wv;
        }
        float s = wave_reduce_add(pu * pi);
        if (lane == 0) {
            s += bu[u] + bi[it] + mu[0];
            s = fminf(fmaxf(s, 1.0f), 5.0f);
            out[p] = s;
        }
    }
}

extern "C" void kernel_launch(void* const* d_in, const int* in_sizes, int n_in,
                              void* d_out, int out_size, void* d_ws, size_t ws_size,
                              hipStream_t stream) {
    const int*   users = (const int*)d_in[0];
    const int*   items = (const int*)d_in[1];
    const int*   ei2   = (const int*)d_in[2];
    const float* ew    = (const float*)d_in[3];
    const float* U     = (const float*)d_in[4];
    const float* I     = (const float*)d_in[5];
    const float* W0    = (const float*)d_in[6];
    const float* b0    = (const float*)d_in[7];
    const float* g0    = (const float*)d_in[8];
    const float* be0   = (const float*)d_in[9];
    const float* W1    = (const float*)d_in[10];
    const float* b1    = (const float*)d_in[11];
    const float* g1    = (const float*)d_in[12];
    const float* be1   = (const float*)d_in[13];
    const float* Wp    = (const float*)d_in[14];
    const float* bp    = (const float*)d_in[15];
    const float* bu    = (const float*)d_in[16];
    const float* bi    = (const float*)d_in[17];
    const float* mu    = (const float*)d_in[18];

    int B = in_sizes[0];
    int E = in_sizes[2] / 2;
    const int* srcp = ei2;
    const int* dstp = ei2 + E;

    // workspace carve-up (256B aligned)
    char* p = (char*)d_ws;
    auto alloc = [&](size_t bytes) -> char* {
        char* r = p;
        p += (bytes + 255) & ~(size_t)255;
        return r;
    };
    float* deg    = (float*)alloc((size_t)NN * 4 * 2);  // deg + counts contiguous (one memset)
    int*   counts = (int*)(deg + NN);
    float* dinv   = (float*)alloc((size_t)NN * 4);
    int*   offs   = (int*)  alloc((size_t)(NN + 1) * 4);
    int*   cursor = (int*)  alloc((size_t)NN * 4);
    int*   parts  = (int*)  alloc(1024 * 4);
    int2*  recs   = (int2*) alloc((size_t)E * 8);
    float* hw2    = (float*)alloc((size_t)NN * D * 4);
    float* h1     = (float*)alloc((size_t)NN * D * 4);
    float* h2     = (float*)alloc((size_t)NN * D * 4);

    hipMemsetAsync(deg, 0, (size_t)NN * 4 * 2, stream);

    int gE = (E + 255) / 256;
    int gN = (NN + 255) / 256;      // 586 blocks, fits in 1024-wide scan2
    int gW = (NN + 3) / 4;          // 4 waves (nodes) per 256-thread block

    k_count<<<gE, 256, 0, stream>>>(dstp, ew, deg, counts, E);
    k_dinv<<<gN, 256, 0, stream>>>(deg, dinv, NN);
    k_scan1<<<gN, 256, 0, stream>>>(counts, offs, parts, NN);
    k_scan2<<<1, 1024, 0, stream>>>(parts, gN);
    k_scan3<<<gN, 256, 0, stream>>>(offs, parts, cursor, NN, E);
    k_fill<<<gE, 256, 0, stream>>>(srcp, dstp, ew, cursor, recs, E);

    // layer 1
    k_gemm<<<2048, 256, 0, stream>>>(nullptr, U, I, W0, dinv, hw2);
    k_conv_pw<<<gW, 256, 0, stream>>>(hw2, offs, recs, dinv, b0, g0, be0,
                                      nullptr, U, I, h1);
    // layer 2
    k_gemm<<<2048, 256, 0, stream>>>(h1, U, I, W1, dinv, hw2);
    k_conv_pw<<<gW, 256, 0, stream>>>(hw2, offs, recs, dinv, b1, g1, be1,
                                      h1, U, I, h2);

    // fused projection + scoring
    k_score<<<512, 256, 0, stream>>>(h2, users, items, Wp, bp, bu, bi, mu,
                                     (float*)d_out, B);
}

// Round 3
// 885.743 us; speedup vs baseline: 1.7395x; 1.5306x over previous
//
#include <hip/hip_runtime.h>

#define NU 100000
#define NI 50000
#define NN 150000   // NU + NI
#define D  64
#define CAP 47      // bucket capacity; E[max degree] ~44 for Poisson(21.3); overflow list handles the rest
#define OVF_MAX 4096

// ---------------- wave helpers ----------------
__device__ __forceinline__ float wave_reduce_add(float v) {
    #pragma unroll
    for (int m = 32; m >= 1; m >>= 1) v += __shfl_xor(v, m, 64);
    return v;
}

// ---------------- bucket fill: ONE atomic per edge, no count pass, no scan ----
__global__ void k_fill(const int* __restrict__ src, const int* __restrict__ dst,
                       const float* __restrict__ ew, int* __restrict__ cursor,
                       int2* __restrict__ recs, int4* __restrict__ ovf,
                       int* __restrict__ ovfcnt, int E) {
    int e = blockIdx.x * blockDim.x + threadIdx.x;
    if (e >= E) return;
    int s = src[e], d = dst[e];
    int w = __float_as_int(ew[e]);
    int slot = atomicAdd(&cursor[d], 1);
    if (slot < CAP) {
        recs[(size_t)d * CAP + slot] = make_int2(s, w);
    } else {
        int o = atomicAdd(ovfcnt, 1);
        if (o < OVF_MAX) ovf[o] = make_int4(d, s, w, 0);
    }
}

// ---------------- weighted degree from buckets (no atomics) ----------------
__global__ void k_deg(const int* __restrict__ cursor, const int2* __restrict__ recs,
                      float* __restrict__ deg) {
    int lane = threadIdx.x & 63;
    int n = blockIdx.x * (blockDim.x >> 6) + (threadIdx.x >> 6);
    if (n >= NN) return;
    int cnt = cursor[n]; if (cnt > CAP) cnt = CAP;
    float w = (lane < cnt) ? __int_as_float(recs[(size_t)n * CAP + lane].y) : 0.0f;
    float s = wave_reduce_add(w);
    if (lane == 0) deg[n] = s;
}

// add overflow-edge weights into deg (normally zero iterations)
__global__ void k_ovf_deg(const int4* __restrict__ ovf, const int* __restrict__ ovfcnt,
                          float* __restrict__ deg) {
    int n = ovfcnt[0]; if (n > OVF_MAX) n = OVF_MAX;
    for (int i = threadIdx.x; i < n; i += blockDim.x)
        atomicAdd(&deg[ovf[i].x], __int_as_float(ovf[i].z));
}

// dinv = rsqrt(deg + 1)   (self-loop weight 1.0 folded in)
__global__ void k_dinv(const float* __restrict__ deg, float* __restrict__ dinv, int n) {
    int i = blockIdx.x * blockDim.x + threadIdx.x;
    if (i < n) dinv[i] = rsqrtf(deg[i] + 1.0f);
}

// ---------------- small GEMM + dinv row-scale: out[n] = dinv[n] * (row(n) @ W) --
__global__ void k_gemm(const float* __restrict__ h, const float* __restrict__ U,
                       const float* __restrict__ I, const float* __restrict__ W,
                       const float* __restrict__ dinv, float* __restrict__ out) {
    __shared__ float Ws[64 * 64];
    for (int i = threadIdx.x; i < 64 * 64; i += blockDim.x) Ws[i] = W[i];
    __syncthreads();
    int lane = threadIdx.x & 63;
    int wpb = blockDim.x >> 6;
    int wid = blockIdx.x * wpb + (threadIdx.x >> 6);
    int tw = gridDim.x * wpb;
    for (int n = wid; n < NN; n += tw) {
        float xv;
        if (h) xv = h[(size_t)n * D + lane];
        else   xv = (n < NU) ? U[(size_t)n * D + lane] : I[(size_t)(n - NU) * D + lane];
        float acc = 0.f;
        #pragma unroll
        for (int k = 0; k < 64; ++k)
            acc += __shfl(xv, k, 64) * Ws[k * 64 + lane];
        out[(size_t)n * D + lane] = acc * dinv[n];
    }
}

// ---------------- conv accumulate for one dst node (wave-cooperative) ---------
__device__ __forceinline__ float conv_accum(int n, int lane,
        const float* __restrict__ hw2, const int* __restrict__ cursor,
        const int2* __restrict__ recs, const int4* __restrict__ ovf,
        const int* __restrict__ ovfcnt) {
    int cnt = cursor[n]; if (cnt > CAP) cnt = CAP;
    int2 rv = make_int2(0, 0);
    if (lane < cnt) rv = recs[(size_t)n * CAP + lane];   // one coalesced bucket read
    float a = hw2[(size_t)n * D + lane];                 // self-loop term
    for (int j = 0; j < cnt; ++j) {
        int   s = __shfl(rv.x, j, 64);
        float w = __int_as_float(__shfl(rv.y, j, 64));
        a += w * hw2[(size_t)s * D + lane];              // independent gathers
    }
    int novf = ovfcnt[0];
    if (novf > 0) {                                      // normally skipped
        if (novf > OVF_MAX) novf = OVF_MAX;
        for (int j = 0; j < novf; ++j) {
            int4 e = ovf[j];
            if (e.x == n) a += __int_as_float(e.z) * hw2[(size_t)e.y * D + lane];
        }
    }
    return a;
}

__device__ __forceinline__ float ln_relu(float v, int lane,
        const float* __restrict__ g, const float* __restrict__ be) {
    float m = wave_reduce_add(v) * (1.0f / 64.0f);
    float dv = v - m;
    float var = wave_reduce_add(dv * dv) * (1.0f / 64.0f);
    return fmaxf(dv * rsqrtf(var + 1e-5f) * g[lane] + be[lane], 0.0f);
}

// ---------------- layer-1 conv (all nodes) + bias + LN + ReLU + residual ------
__global__ __launch_bounds__(256) void k_conv1(
        const float* __restrict__ hw2, const int* __restrict__ cursor,
        const int2* __restrict__ recs, const int4* __restrict__ ovf,
        const int* __restrict__ ovfcnt, const float* __restrict__ dinv,
        const float* __restrict__ b, const float* __restrict__ g,
        const float* __restrict__ be, const float* __restrict__ U,
        const float* __restrict__ I, float* __restrict__ out) {
    int lane = threadIdx.x & 63;
    int n = blockIdx.x * 4 + (threadIdx.x >> 6);
    if (n >= NN) return;
    float a = conv_accum(n, lane, hw2, cursor, recs, ovf, ovfcnt);
    float v = a * dinv[n] + b[lane];
    float y = ln_relu(v, lane, g, be);
    float r = (n < NU) ? U[(size_t)n * D + lane] : I[(size_t)(n - NU) * D + lane];
    out[(size_t)n * D + lane] = y + r;
}

// ---------------- layer-2 conv ONLY for sampled nodes -------------------------
// p in [0,B): user sample p; p in [B,2B): item sample p-B
__global__ __launch_bounds__(256) void k_conv2s(
        const float* __restrict__ hw2, const int* __restrict__ cursor,
        const int2* __restrict__ recs, const int4* __restrict__ ovf,
        const int* __restrict__ ovfcnt, const float* __restrict__ dinv,
        const float* __restrict__ b, const float* __restrict__ g,
        const float* __restrict__ be, const int* __restrict__ users,
        const int* __restrict__ items, const float* __restrict__ h1,
        float* __restrict__ h2s, int B) {
    int lane = threadIdx.x & 63;
    int p = blockIdx.x * 4 + (threadIdx.x >> 6);
    if (p >= 2 * B) return;
    int n = (p < B) ? users[p] : NU + items[p - B];
    float a = conv_accum(n, lane, hw2, cursor, recs, ovf, ovfcnt);
    float v = a * dinv[n] + b[lane];
    float y = ln_relu(v, lane, g, be);
    h2s[(size_t)p * D + lane] = y + h1[(size_t)n * D + lane];
}

// ---------------- fused projection + scoring ----------------
__global__ void k_score(const float* __restrict__ h2s, const int* __restrict__ users,
                        const int* __restrict__ items, const float* __restrict__ Wp,
                        const float* __restrict__ bp, const float* __restrict__ bu,
                        const float* __restrict__ bi, const float* __restrict__ mu,
                        float* __restrict__ out, int B) {
    __shared__ float Ws[64 * 64];
    for (int i = threadIdx.x; i < 64 * 64; i += blockDim.x) Ws[i] = Wp[i];
    __syncthreads();
    int lane = threadIdx.x & 63;
    int wpb = blockDim.x >> 6;
    int wid = blockIdx.x * wpb + (threadIdx.x >> 6);
    int tw = gridDim.x * wpb;
    for (int p = wid; p < B; p += tw) {
        float hu = h2s[(size_t)p * D + lane];
        float hi = h2s[(size_t)(B + p) * D + lane];
        float pu = bp[lane], pi = bp[lane];
        #pragma unroll
        for (int k = 0; k < 64; ++k) {
            float wv = Ws[k * 64 + lane];
            pu += __shfl(hu, k, 64) * wv;
            pi += __shfl(hi, k, 64) * wv;
        }
        float s = wave_reduce_add(pu * pi);
        if (lane == 0) {
            s += bu[users[p]] + bi[items[p]] + mu[0];
            out[p] = fminf(fmaxf(s, 1.0f), 5.0f);
        }
    }
}

extern "C" void kernel_launch(void* const* d_in, const int* in_sizes, int n_in,
                              void* d_out, int out_size, void* d_ws, size_t ws_size,
                              hipStream_t stream) {
    const int*   users = (const int*)d_in[0];
    const int*   items = (const int*)d_in[1];
    const int*   ei2   = (const int*)d_in[2];
    const float* ew    = (const float*)d_in[3];
    const float* U     = (const float*)d_in[4];
    const float* I     = (const float*)d_in[5];
    const float* W0    = (const float*)d_in[6];
    const float* b0    = (const float*)d_in[7];
    const float* g0    = (const float*)d_in[8];
    const float* be0   = (const float*)d_in[9];
    const float* W1    = (const float*)d_in[10];
    const float* b1    = (const float*)d_in[11];
    const float* g1    = (const float*)d_in[12];
    const float* be1   = (const float*)d_in[13];
    const float* Wp    = (const float*)d_in[14];
    const float* bp    = (const float*)d_in[15];
    const float* bu    = (const float*)d_in[16];
    const float* bi    = (const float*)d_in[17];
    const float* mu    = (const float*)d_in[18];

    int B = in_sizes[0];
    int E = in_sizes[2] / 2;
    const int* srcp = ei2;
    const int* dstp = ei2 + E;

    // workspace carve-up (256B aligned); total ~143.5 MB (<= proven-safe 143.9)
    char* p = (char*)d_ws;
    auto alloc = [&](size_t bytes) -> char* {
        char* r = p;
        p += (bytes + 255) & ~(size_t)255;
        return r;
    };
    float* deg    = (float*)alloc((size_t)NN * 4);
    int*   cursor = (int*)  alloc((size_t)NN * 4);
    float* dinv   = (float*)alloc((size_t)NN * 4);
    int*   ovfcnt = (int*)  alloc(256);
    int4*  ovf    = (int4*) alloc((size_t)OVF_MAX * 16);
    int2*  recs   = (int2*) alloc((size_t)NN * CAP * 8);   // 56.4 MB
    float* bufA   = (float*)alloc((size_t)NN * D * 4);     // hw2 (both layers)
    float* bufB   = (float*)alloc((size_t)NN * D * 4);     // h1
    float* h2s    = (float*)alloc((size_t)2 * B * D * 4);  // sampled layer-2 out

    hipMemsetAsync(cursor, 0, (size_t)NN * 4, stream);
    hipMemsetAsync(ovfcnt, 0, 4, stream);

    int gE = (E + 255) / 256;
    int gN = (NN + 255) / 256;
    int gW = (NN + 3) / 4;          // one wave per node, 4 waves/block
    int gS = (2 * B + 3) / 4;       // one wave per sample

    k_fill<<<gE, 256, 0, stream>>>(srcp, dstp, ew, cursor, recs, ovf, ovfcnt, E);
    k_deg<<<gW, 256, 0, stream>>>(cursor, recs, deg);
    k_ovf_deg<<<1, 256, 0, stream>>>(ovf, ovfcnt, deg);
    k_dinv<<<gN, 256, 0, stream>>>(deg, dinv, NN);

    // layer 1 (all nodes)
    k_gemm<<<2048, 256, 0, stream>>>(nullptr, U, I, W0, dinv, bufA);
    k_conv1<<<gW, 256, 0, stream>>>(bufA, cursor, recs, ovf, ovfcnt, dinv,
                                    b0, g0, be0, U, I, bufB);
    // layer 2 (gemm all nodes; conv only sampled nodes)
    k_gemm<<<2048, 256, 0, stream>>>(bufB, U, I, W1, dinv, bufA);
    k_conv2s<<<gS, 256, 0, stream>>>(bufA, cursor, recs, ovf, ovfcnt, dinv,
                                     b1, g1, be1, users, items, bufB, h2s, B);

    // fused projection + scoring
    k_score<<<512, 256, 0, stream>>>(h2s, users, items, Wp, bp, bu, bi, mu,
                                     (float*)d_out, B);
}

// Round 4
// 864.577 us; speedup vs baseline: 1.7821x; 1.0245x over previous
//
#include <hip/hip_runtime.h>

#define NU 100000
#define NI 50000
#define NN 150000   // NU + NI
#define D  64
#define CAP 47      // bucket capacity; E[max in-degree] ~44 for Poisson(21.3)
#define OVF_MAX 4096

typedef unsigned int uint;
typedef unsigned short ushort;

// ---------------- helpers ----------------
__device__ __forceinline__ float wave_reduce_add(float v) {
    #pragma unroll
    for (int m = 32; m >= 1; m >>= 1) v += __shfl_xor(v, m, 64);
    return v;
}
__device__ __forceinline__ float bf2f(ushort u) {
    union { uint i; float f; } c; c.i = ((uint)u) << 16; return c.f;
}
__device__ __forceinline__ ushort f2bf(float f) {   // round-to-nearest-even
    union { float f; uint i; } c; c.f = f;
    uint r = c.i + 0x7FFF + ((c.i >> 16) & 1);
    return (ushort)(r >> 16);
}
// edge record: [31:18] weight q14, [17:0] src id
__device__ __forceinline__ uint enc_rec(int s, float w) {
    int q = (int)(w * 16384.0f);
    q = (q < 0) ? 0 : (q > 16383 ? 16383 : q);
    return ((uint)q << 18) | (uint)s;
}

// ---------------- bucket fill: ONE atomic per edge ----------------
__global__ void k_fill(const int* __restrict__ src, const int* __restrict__ dst,
                       const float* __restrict__ ew, int* __restrict__ cursor,
                       uint* __restrict__ recs, int4* __restrict__ ovf,
                       int* __restrict__ ovfcnt, int E) {
    int e = blockIdx.x * blockDim.x + threadIdx.x;
    if (e >= E) return;
    int s = src[e], d = dst[e];
    float w = ew[e];
    int slot = atomicAdd(&cursor[d], 1);
    if (slot < CAP) {
        recs[(size_t)d * CAP + slot] = enc_rec(s, w);
    } else {
        int o = atomicAdd(ovfcnt, 1);
        if (o < OVF_MAX) ovf[o] = make_int4(d, s, __float_as_int(w), 0);
    }
}

// ---------------- fused deg + dinv from buckets (no atomics) ----------------
__global__ void k_degdinv(const int* __restrict__ cursor, const uint* __restrict__ recs,
                          float* __restrict__ deg, float* __restrict__ dinv) {
    int lane = threadIdx.x & 63;
    int n = blockIdx.x * (blockDim.x >> 6) + (threadIdx.x >> 6);
    if (n >= NN) return;
    int cnt = cursor[n]; if (cnt > CAP) cnt = CAP;
    float w = 0.0f;
    if (lane < cnt) w = (float)(recs[(size_t)n * CAP + lane] >> 18) * (1.0f / 16384.0f);
    float s = wave_reduce_add(w);
    if (lane == 0) {
        deg[n] = s;
        dinv[n] = rsqrtf(s + 1.0f);   // self-loop weight 1 folded in
    }
}

// overflow fixup: single thread, normally zero-trip; handles duplicate dsts safely
__global__ void k_ovf_fix(const int4* __restrict__ ovf, const int* __restrict__ ovfcnt,
                          float* __restrict__ deg, float* __restrict__ dinv) {
    if (threadIdx.x != 0 || blockIdx.x != 0) return;
    int n = ovfcnt[0]; if (n > OVF_MAX) n = OVF_MAX;
    for (int i = 0; i < n; ++i) {
        int d = ovf[i].x;
        float dg = deg[d] + __int_as_float(ovf[i].z);
        deg[d] = dg;
        dinv[d] = rsqrtf(dg + 1.0f);
    }
}

// ------- small GEMM + dinv row-scale, bf16 out: out[n] = bf16(dinv[n]*(row(n)@W)) --
__global__ void k_gemm(const float* __restrict__ h, const float* __restrict__ U,
                       const float* __restrict__ I, const float* __restrict__ W,
                       const float* __restrict__ dinv, ushort* __restrict__ out) {
    __shared__ float Ws[64 * 64];
    for (int i = threadIdx.x; i < 64 * 64; i += blockDim.x) Ws[i] = W[i];
    __syncthreads();
    int lane = threadIdx.x & 63;
    int wpb = blockDim.x >> 6;
    int wid = blockIdx.x * wpb + (threadIdx.x >> 6);
    int tw = gridDim.x * wpb;
    for (int n = wid; n < NN; n += tw) {
        float xv;
        if (h) xv = h[(size_t)n * D + lane];
        else   xv = (n < NU) ? U[(size_t)n * D + lane] : I[(size_t)(n - NU) * D + lane];
        float acc = 0.f;
        #pragma unroll
        for (int k = 0; k < 64; ++k)
            acc += __shfl(xv, k, 64) * Ws[k * 64 + lane];
        out[(size_t)n * D + lane] = f2bf(acc * dinv[n]);
    }
}

// ---------------- conv accumulate for one dst node (wave-cooperative) ---------
__device__ __forceinline__ float conv_accum(int n, int lane,
        const ushort* __restrict__ hw2b, const int* __restrict__ cursor,
        const uint* __restrict__ recs, const int4* __restrict__ ovf,
        const int* __restrict__ ovfcnt) {
    int cnt = cursor[n]; if (cnt > CAP) cnt = CAP;
    uint rv = (lane < cnt) ? recs[(size_t)n * CAP + lane] : 0u;  // coalesced bucket read
    float a = bf2f(hw2b[(size_t)n * D + lane]);                  // self-loop term
    for (int j = 0; j < cnt; ++j) {
        uint r = (uint)__shfl((int)rv, j, 64);                   // one shfl per edge
        int   s = (int)(r & 0x3FFFFu);
        float w = (float)(r >> 18) * (1.0f / 16384.0f);
        a = fmaf(w, bf2f(hw2b[(size_t)s * D + lane]), a);        // independent gathers
    }
    int novf = ovfcnt[0];
    if (novf > 0) {                                              // normally skipped
        if (novf > OVF_MAX) novf = OVF_MAX;
        for (int j = 0; j < novf; ++j) {
            int4 e = ovf[j];
            if (e.x == n) a = fmaf(__int_as_float(e.z),
                                   bf2f(hw2b[(size_t)e.y * D + lane]), a);
        }
    }
    return a;
}

__device__ __forceinline__ float ln_relu(float v, int lane,
        const float* __restrict__ g, const float* __restrict__ be) {
    float m = wave_reduce_add(v) * (1.0f / 64.0f);
    float dv = v - m;
    float var = wave_reduce_add(dv * dv) * (1.0f / 64.0f);
    return fmaxf(dv * rsqrtf(var + 1e-5f) * g[lane] + be[lane], 0.0f);
}

// ---------------- layer-1 conv (all nodes) + bias + LN + ReLU + residual ------
__global__ __launch_bounds__(256) void k_conv1(
        const ushort* __restrict__ hw2b, const int* __restrict__ cursor,
        const uint* __restrict__ recs, const int4* __restrict__ ovf,
        const int* __restrict__ ovfcnt, const float* __restrict__ dinv,
        const float* __restrict__ b, const float* __restrict__ g,
        const float* __restrict__ be, const float* __restrict__ U,
        const float* __restrict__ I, float* __restrict__ out) {
    int lane = threadIdx.x & 63;
    int n = blockIdx.x * 4 + (threadIdx.x >> 6);
    if (n >= NN) return;
    float a = conv_accum(n, lane, hw2b, cursor, recs, ovf, ovfcnt);
    float v = a * dinv[n] + b[lane];
    float y = ln_relu(v, lane, g, be);
    float r = (n < NU) ? U[(size_t)n * D + lane] : I[(size_t)(n - NU) * D + lane];
    out[(size_t)n * D + lane] = y + r;
}

// ---------------- layer-2 conv ONLY for sampled nodes -------------------------
__global__ __launch_bounds__(256) void k_conv2s(
        const ushort* __restrict__ hw2b, const int* __restrict__ cursor,
        const uint* __restrict__ recs, const int4* __restrict__ ovf,
        const int* __restrict__ ovfcnt, const float* __restrict__ dinv,
        const float* __restrict__ b, const float* __restrict__ g,
        const float* __restrict__ be, const int* __restrict__ users,
        const int* __restrict__ items, const float* __restrict__ h1,
        float* __restrict__ h2s, int B) {
    int lane = threadIdx.x & 63;
    int p = blockIdx.x * 4 + (threadIdx.x >> 6);
    if (p >= 2 * B) return;
    int n = (p < B) ? users[p] : NU + items[p - B];
    float a = conv_accum(n, lane, hw2b, cursor, recs, ovf, ovfcnt);
    float v = a * dinv[n] + b[lane];
    float y = ln_relu(v, lane, g, be);
    h2s[(size_t)p * D + lane] = y + h1[(size_t)n * D + lane];
}

// ---------------- fused projection + scoring ----------------
__global__ void k_score(const float* __restrict__ h2s, const int* __restrict__ users,
                        const int* __restrict__ items, const float* __restrict__ Wp,
                        const float* __restrict__ bp, const float* __restrict__ bu,
                        const float* __restrict__ bi, const float* __restrict__ mu,
                        float* __restrict__ out, int B) {
    __shared__ float Ws[64 * 64];
    for (int i = threadIdx.x; i < 64 * 64; i += blockDim.x) Ws[i] = Wp[i];
    __syncthreads();
    int lane = threadIdx.x & 63;
    int wpb = blockDim.x >> 6;
    int wid = blockIdx.x * wpb + (threadIdx.x >> 6);
    int tw = gridDim.x * wpb;
    for (int p = wid; p < B; p += tw) {
        float hu = h2s[(size_t)p * D + lane];
        float hi = h2s[(size_t)(B + p) * D + lane];
        float pu = bp[lane], pi = bp[lane];
        #pragma unroll
        for (int k = 0; k < 64; ++k) {
            float wv = Ws[k * 64 + lane];
            pu += __shfl(hu, k, 64) * wv;
            pi += __shfl(hi, k, 64) * wv;
        }
        float s = wave_reduce_add(pu * pi);
        if (lane == 0) {
            s += bu[users[p]] + bi[items[p]] + mu[0];
            out[p] = fminf(fmaxf(s, 1.0f), 5.0f);
        }
    }
}

extern "C" void kernel_launch(void* const* d_in, const int* in_sizes, int n_in,
                              void* d_out, int out_size, void* d_ws, size_t ws_size,
                              hipStream_t stream) {
    const int*   users = (const int*)d_in[0];
    const int*   items = (const int*)d_in[1];
    const int*   ei2   = (const int*)d_in[2];
    const float* ew    = (const float*)d_in[3];
    const float* U     = (const float*)d_in[4];
    const float* I     = (const float*)d_in[5];
    const float* W0    = (const float*)d_in[6];
    const float* b0    = (const float*)d_in[7];
    const float* g0    = (const float*)d_in[8];
    const float* be0   = (const float*)d_in[9];
    const float* W1    = (const float*)d_in[10];
    const float* b1    = (const float*)d_in[11];
    const float* g1    = (const float*)d_in[12];
    const float* be1   = (const float*)d_in[13];
    const float* Wp    = (const float*)d_in[14];
    const float* bp    = (const float*)d_in[15];
    const float* bu    = (const float*)d_in[16];
    const float* bi    = (const float*)d_in[17];
    const float* mu    = (const float*)d_in[18];

    int B = in_sizes[0];
    int E = in_sizes[2] / 2;
    const int* srcp = ei2;
    const int* dstp = ei2 + E;

    // workspace carve-up (256B aligned); total ~105 MB
    char* p = (char*)d_ws;
    auto alloc = [&](size_t bytes) -> char* {
        char* r = p;
        p += (bytes + 255) & ~(size_t)255;
        return r;
    };
    float*  deg    = (float*)alloc((size_t)NN * 4);
    int*    cursor = (int*)  alloc((size_t)NN * 4);
    float*  dinv   = (float*)alloc((size_t)NN * 4);
    int*    ovfcnt = (int*)  alloc(256);
    int4*   ovf    = (int4*) alloc((size_t)OVF_MAX * 16);
    uint*   recs   = (uint*) alloc((size_t)NN * CAP * 4);   // 28.2 MB
    ushort* hw2b   = (ushort*)alloc((size_t)NN * D * 2);    // bf16 messages, 19.2 MB
    float*  h1     = (float*)alloc((size_t)NN * D * 4);     // 38.4 MB
    float*  h2s    = (float*)alloc((size_t)2 * B * D * 4);  // 16.8 MB

    hipMemsetAsync(cursor, 0, (size_t)NN * 4, stream);
    hipMemsetAsync(ovfcnt, 0, 4, stream);

    int gE = (E + 255) / 256;
    int gW = (NN + 3) / 4;          // one wave per node, 4 waves/block
    int gS = (2 * B + 3) / 4;       // one wave per sample

    k_fill<<<gE, 256, 0, stream>>>(srcp, dstp, ew, cursor, recs, ovf, ovfcnt, E);
    k_degdinv<<<gW, 256, 0, stream>>>(cursor, recs, deg, dinv);
    k_ovf_fix<<<1, 64, 0, stream>>>(ovf, ovfcnt, deg, dinv);

    // layer 1 (all nodes)
    k_gemm<<<2048, 256, 0, stream>>>(nullptr, U, I, W0, dinv, hw2b);
    k_conv1<<<gW, 256, 0, stream>>>(hw2b, cursor, recs, ovf, ovfcnt, dinv,
                                    b0, g0, be0, U, I, h1);
    // layer 2 (gemm all nodes; conv only sampled nodes)
    k_gemm<<<2048, 256, 0, stream>>>(h1, U, I, W1, dinv, hw2b);
    k_conv2s<<<gS, 256, 0, stream>>>(hw2b, cursor, recs, ovf, ovfcnt, dinv,
                                     b1, g1, be1, users, items, h1, h2s, B);

    // fused projection + scoring
    k_score<<<512, 256, 0, stream>>>(h2s, users, items, Wp, bp, bu, bi, mu,
                                     (float*)d_out, B);
}

// Round 5
// 526.770 us; speedup vs baseline: 2.9249x; 1.6413x over previous
//
#include <hip/hip_runtime.h>

#define NU 100000
#define NI 50000
#define NN 150000   // NU + NI
#define D  64
#define CAP 47      // bucket capacity; E[max in-degree] ~44 for Poisson(21.3)
#define OVF_MAX 4096

typedef unsigned int uint;
typedef unsigned short ushort;

// ---------------- helpers ----------------
__device__ __forceinline__ float wave_reduce_add(float v) {
    #pragma unroll
    for (int m = 32; m >= 1; m >>= 1) v += __shfl_xor(v, m, 64);
    return v;
}
__device__ __forceinline__ float bf2f(ushort u) {
    union { uint i; float f; } c; c.i = ((uint)u) << 16; return c.f;
}
__device__ __forceinline__ ushort f2bf(float f) {   // round-to-nearest-even
    union { float f; uint i; } c; c.f = f;
    uint r = c.i + 0x7FFF + ((c.i >> 16) & 1);
    return (ushort)(r >> 16);
}
__device__ __forceinline__ float lane_bcast(float v, int l) {  // uniform l, no LDS
    return __int_as_float(__builtin_amdgcn_readlane(__float_as_int(v), l));
}
// edge record: [31:18] weight q14, [17:0] src id
__device__ __forceinline__ uint enc_rec(int s, float w) {
    int q = (int)(w * 16384.0f);
    q = (q < 0) ? 0 : (q > 16383 ? 16383 : q);
    return ((uint)q << 18) | (uint)s;
}

// ---------------- bucket fill: ONE atomic per edge ----------------
__global__ void k_fill(const int* __restrict__ src, const int* __restrict__ dst,
                       const float* __restrict__ ew, int* __restrict__ cursor,
                       uint* __restrict__ recs, int4* __restrict__ ovf,
                       int* __restrict__ ovfcnt, int E) {
    int e = blockIdx.x * blockDim.x + threadIdx.x;
    if (e >= E) return;
    int s = src[e], d = dst[e];
    float w = ew[e];
    int slot = atomicAdd(&cursor[d], 1);
    if (slot < CAP) {
        recs[(size_t)d * CAP + slot] = enc_rec(s, w);
    } else {
        int o = atomicAdd(ovfcnt, 1);
        if (o < OVF_MAX) ovf[o] = make_int4(d, s, __float_as_int(w), 0);
    }
}

// ---------------- fused deg + dinv from buckets (no atomics) ----------------
__global__ void k_degdinv(const int* __restrict__ cursor, const uint* __restrict__ recs,
                          float* __restrict__ deg, float* __restrict__ dinv) {
    int lane = threadIdx.x & 63;
    int n = blockIdx.x * (blockDim.x >> 6) + (threadIdx.x >> 6);
    if (n >= NN) return;
    int cnt = cursor[n]; if (cnt > CAP) cnt = CAP;
    float w = 0.0f;
    if (lane < cnt) w = (float)(recs[(size_t)n * CAP + lane] >> 18) * (1.0f / 16384.0f);
    float s = wave_reduce_add(w);
    if (lane == 0) {
        deg[n] = s;
        dinv[n] = rsqrtf(s + 1.0f);   // self-loop weight 1 folded in
    }
}

// overflow fixup: single thread, normally zero-trip; handles duplicate dsts safely
__global__ void k_ovf_fix(const int4* __restrict__ ovf, const int* __restrict__ ovfcnt,
                          float* __restrict__ deg, float* __restrict__ dinv) {
    if (threadIdx.x != 0 || blockIdx.x != 0) return;
    int n = ovfcnt[0]; if (n > OVF_MAX) n = OVF_MAX;
    for (int i = 0; i < n; ++i) {
        int d = ovf[i].x;
        float dg = deg[d] + __int_as_float(ovf[i].z);
        deg[d] = dg;
        dinv[d] = rsqrtf(dg + 1.0f);
    }
}

// ------- small GEMM + dinv row-scale, bf16 out: out[n] = bf16(dinv[n]*(row(n)@W)) --
__global__ void k_gemm(const float* __restrict__ h, const float* __restrict__ U,
                       const float* __restrict__ I, const float* __restrict__ W,
                       const float* __restrict__ dinv, ushort* __restrict__ out) {
    __shared__ float Ws[64 * 64];
    for (int i = threadIdx.x; i < 64 * 64; i += blockDim.x) Ws[i] = W[i];
    __syncthreads();
    int lane = threadIdx.x & 63;
    int wpb = blockDim.x >> 6;
    int wid = blockIdx.x * wpb + (threadIdx.x >> 6);
    int tw = gridDim.x * wpb;
    for (int n = wid; n < NN; n += tw) {
        float xv;
        if (h) xv = h[(size_t)n * D + lane];
        else   xv = (n < NU) ? U[(size_t)n * D + lane] : I[(size_t)(n - NU) * D + lane];
        float acc = 0.f;
        #pragma unroll
        for (int k = 0; k < 64; ++k)
            acc = fmaf(lane_bcast(xv, k), Ws[k * 64 + lane], acc);
        out[(size_t)n * D + lane] = f2bf(acc * dinv[n]);
    }
}

// ---------------- conv accumulate for one dst node (wave-cooperative) ---------
// Branch-free readlane chunks: padded slots decode to w=0, s=0 (gather of row 0,
// L1-broadcast, contributes 0) -> deep back-to-back gather issue, no LDS shfl.
__device__ __forceinline__ float conv_accum(int n, int lane,
        const ushort* __restrict__ hw2b, const int* __restrict__ cursor,
        const uint* __restrict__ recs, const int4* __restrict__ ovf,
        const int* __restrict__ ovfcnt) {
    int cnt = __builtin_amdgcn_readfirstlane(cursor[n]);
    if (cnt > CAP) cnt = CAP;
    uint rv = (lane < cnt) ? recs[(size_t)n * CAP + lane] : 0u;  // coalesced bucket read
    float a = bf2f(hw2b[(size_t)n * D + lane]);                  // self-loop term
    int cp = (cnt + 7) & ~7;                                     // pad to chunk of 8
    for (int j0 = 0; j0 < cp; j0 += 8) {
        #pragma unroll
        for (int k = 0; k < 8; ++k) {
            uint r = (uint)__builtin_amdgcn_readlane((int)rv, j0 + k);  // scalar record
            int   s = (int)(r & 0x3FFFFu);
            float w = (float)(r >> 18) * (1.0f / 16384.0f);
            a = fmaf(w, bf2f(hw2b[(size_t)s * D + lane]), a);
        }
    }
    int novf = __builtin_amdgcn_readfirstlane(ovfcnt[0]);
    if (novf > 0) {                                              // normally skipped
        if (novf > OVF_MAX) novf = OVF_MAX;
        for (int j = 0; j < novf; ++j) {
            int4 e = ovf[j];
            if (e.x == n) a = fmaf(__int_as_float(e.z),
                                   bf2f(hw2b[(size_t)e.y * D + lane]), a);
        }
    }
    return a;
}

__device__ __forceinline__ float ln_relu(float v, int lane,
        const float* __restrict__ g, const float* __restrict__ be) {
    float m = wave_reduce_add(v) * (1.0f / 64.0f);
    float dv = v - m;
    float var = wave_reduce_add(dv * dv) * (1.0f / 64.0f);
    return fmaxf(dv * rsqrtf(var + 1e-5f) * g[lane] + be[lane], 0.0f);
}

// ---------------- layer-1 conv (all nodes) + bias + LN + ReLU + residual ------
__global__ __launch_bounds__(256) void k_conv1(
        const ushort* __restrict__ hw2b, const int* __restrict__ cursor,
        const uint* __restrict__ recs, const int4* __restrict__ ovf,
        const int* __restrict__ ovfcnt, const float* __restrict__ dinv,
        const float* __restrict__ b, const float* __restrict__ g,
        const float* __restrict__ be, const float* __restrict__ U,
        const float* __restrict__ I, float* __restrict__ out) {
    int lane = threadIdx.x & 63;
    int n = __builtin_amdgcn_readfirstlane(blockIdx.x * 4 + (threadIdx.x >> 6));
    if (n >= NN) return;
    float a = conv_accum(n, lane, hw2b, cursor, recs, ovf, ovfcnt);
    float v = a * dinv[n] + b[lane];
    float y = ln_relu(v, lane, g, be);
    float r = (n < NU) ? U[(size_t)n * D + lane] : I[(size_t)(n - NU) * D + lane];
    out[(size_t)n * D + lane] = y + r;
}

// ---------------- layer-2 conv ONLY for sampled nodes -------------------------
__global__ __launch_bounds__(256) void k_conv2s(
        const ushort* __restrict__ hw2b, const int* __restrict__ cursor,
        const uint* __restrict__ recs, const int4* __restrict__ ovf,
        const int* __restrict__ ovfcnt, const float* __restrict__ dinv,
        const float* __restrict__ b, const float* __restrict__ g,
        const float* __restrict__ be, const int* __restrict__ users,
        const int* __restrict__ items, const float* __restrict__ h1,
        float* __restrict__ h2s, int B) {
    int lane = threadIdx.x & 63;
    int p = blockIdx.x * 4 + (threadIdx.x >> 6);
    if (p >= 2 * B) return;
    int n = (p < B) ? users[p] : NU + items[p - B];
    n = __builtin_amdgcn_readfirstlane(n);
    float a = conv_accum(n, lane, hw2b, cursor, recs, ovf, ovfcnt);
    float v = a * dinv[n] + b[lane];
    float y = ln_relu(v, lane, g, be);
    h2s[(size_t)p * D + lane] = y + h1[(size_t)n * D + lane];
}

// ---------------- fused projection + scoring ----------------
__global__ void k_score(const float* __restrict__ h2s, const int* __restrict__ users,
                        const int* __restrict__ items, const float* __restrict__ Wp,
                        const float* __restrict__ bp, const float* __restrict__ bu,
                        const float* __restrict__ bi, const float* __restrict__ mu,
                        float* __restrict__ out, int B) {
    __shared__ float Ws[64 * 64];
    for (int i = threadIdx.x; i < 64 * 64; i += blockDim.x) Ws[i] = Wp[i];
    __syncthreads();
    int lane = threadIdx.x & 63;
    int wpb = blockDim.x >> 6;
    int wid = blockIdx.x * wpb + (threadIdx.x >> 6);
    int tw = gridDim.x * wpb;
    for (int p = wid; p < B; p += tw) {
        float hu = h2s[(size_t)p * D + lane];
        float hi = h2s[(size_t)(B + p) * D + lane];
        float pu = bp[lane], pi = bp[lane];
        #pragma unroll
        for (int k = 0; k < 64; ++k) {
            float wv = Ws[k * 64 + lane];
            pu = fmaf(lane_bcast(hu, k), wv, pu);
            pi = fmaf(lane_bcast(hi, k), wv, pi);
        }
        float s = wave_reduce_add(pu * pi);
        if (lane == 0) {
            s += bu[users[p]] + bi[items[p]] + mu[0];
            out[p] = fminf(fmaxf(s, 1.0f), 5.0f);
        }
    }
}

extern "C" void kernel_launch(void* const* d_in, const int* in_sizes, int n_in,
                              void* d_out, int out_size, void* d_ws, size_t ws_size,
                              hipStream_t stream) {
    const int*   users = (const int*)d_in[0];
    const int*   items = (const int*)d_in[1];
    const int*   ei2   = (const int*)d_in[2];
    const float* ew    = (const float*)d_in[3];
    const float* U     = (const float*)d_in[4];
    const float* I     = (const float*)d_in[5];
    const float* W0    = (const float*)d_in[6];
    const float* b0    = (const float*)d_in[7];
    const float* g0    = (const float*)d_in[8];
    const float* be0   = (const float*)d_in[9];
    const float* W1    = (const float*)d_in[10];
    const float* b1    = (const float*)d_in[11];
    const float* g1    = (const float*)d_in[12];
    const float* be1   = (const float*)d_in[13];
    const float* Wp    = (const float*)d_in[14];
    const float* bp    = (const float*)d_in[15];
    const float* bu    = (const float*)d_in[16];
    const float* bi    = (const float*)d_in[17];
    const float* mu    = (const float*)d_in[18];

    int B = in_sizes[0];
    int E = in_sizes[2] / 2;
    const int* srcp = ei2;
    const int* dstp = ei2 + E;

    // workspace carve-up (256B aligned); total ~105 MB
    char* p = (char*)d_ws;
    auto alloc = [&](size_t bytes) -> char* {
        char* r = p;
        p += (bytes + 255) & ~(size_t)255;
        return r;
    };
    float*  deg    = (float*)alloc((size_t)NN * 4);
    int*    cursor = (int*)  alloc((size_t)NN * 4);
    float*  dinv   = (float*)alloc((size_t)NN * 4);
    int*    ovfcnt = (int*)  alloc(256);
    int4*   ovf    = (int4*) alloc((size_t)OVF_MAX * 16);
    uint*   recs   = (uint*) alloc((size_t)NN * CAP * 4);   // 28.2 MB
    ushort* hw2b   = (ushort*)alloc((size_t)NN * D * 2);    // bf16 messages, 19.2 MB
    float*  h1     = (float*)alloc((size_t)NN * D * 4);     // 38.4 MB
    float*  h2s    = (float*)alloc((size_t)2 * B * D * 4);  // 16.8 MB

    hipMemsetAsync(cursor, 0, (size_t)NN * 4, stream);
    hipMemsetAsync(ovfcnt, 0, 4, stream);

    int gE = (E + 255) / 256;
    int gW = (NN + 3) / 4;          // one wave per node, 4 waves/block
    int gS = (2 * B + 3) / 4;       // one wave per sample

    k_fill<<<gE, 256, 0, stream>>>(srcp, dstp, ew, cursor, recs, ovf, ovfcnt, E);
    k_degdinv<<<gW, 256, 0, stream>>>(cursor, recs, deg, dinv);
    k_ovf_fix<<<1, 64, 0, stream>>>(ovf, ovfcnt, deg, dinv);

    // layer 1 (all nodes)
    k_gemm<<<2048, 256, 0, stream>>>(nullptr, U, I, W0, dinv, hw2b);
    k_conv1<<<gW, 256, 0, stream>>>(hw2b, cursor, recs, ovf, ovfcnt, dinv,
                                    b0, g0, be0, U, I, h1);
    // layer 2 (gemm all nodes; conv only sampled nodes)
    k_gemm<<<2048, 256, 0, stream>>>(h1, U, I, W1, dinv, hw2b);
    k_conv2s<<<gS, 256, 0, stream>>>(hw2b, cursor, recs, ovf, ovfcnt, dinv,
                                     b1, g1, be1, users, items, h1, h2s, B);

    // fused projection + scoring
    k_score<<<512, 256, 0, stream>>>(h2s, users, items, Wp, bp, bu, bi, mu,
                                     (float*)d_out, B);
}

// Round 6
// 476.113 us; speedup vs baseline: 3.2361x; 1.1064x over previous
//
#include <hip/hip_runtime.h>

#define NU 100000
#define NI 50000
#define NN 150000   // NU + NI
#define D  64
#define CAP 47      // bucket capacity per dst; E[max in-degree] ~44 for Poisson(21.3)
#define OVF_MAX 4096

// binning params
#define BINSHIFT 9
#define BINW 512                 // dsts per bin
#define NBINS 293                // ceil(150000/512); 293*512 = 150016
#define BINCAP 11448             // per-bin record cap (mean 10923 + 5 sigma), multiple of 8
#define STAGE_CAP 20             // LDS stage slots per bin
#define EPT 4                    // edges per thread per batch (batch = 1024 edges)
#define SPILL_CAP 262144

typedef unsigned int uint;
typedef unsigned short ushort;

// ---------------- helpers ----------------
__device__ __forceinline__ float wave_reduce_add(float v) {
    #pragma unroll
    for (int m = 32; m >= 1; m >>= 1) v += __shfl_xor(v, m, 64);
    return v;
}
__device__ __forceinline__ float bf2f(ushort u) {
    union { uint i; float f; } c; c.i = ((uint)u) << 16; return c.f;
}
__device__ __forceinline__ ushort f2bf(float f) {   // round-to-nearest-even
    union { float f; uint i; } c; c.f = f;
    uint r = c.i + 0x7FFF + ((c.i >> 16) & 1);
    return (ushort)(r >> 16);
}
__device__ __forceinline__ float lane_bcast(float v, int l) {  // uniform l, no LDS
    return __int_as_float(__builtin_amdgcn_readlane(__float_as_int(v), l));
}
__device__ __forceinline__ uint q14(float w) {
    int q = (int)(w * 16384.0f);
    q = (q < 0) ? 0 : (q > 16383 ? 16383 : q);
    return (uint)q;
}
// spill entry: word0 = src18 | q14<<18 ; word1 = dst
__device__ __forceinline__ void spill_one(int d, uint s, float w,
        uint2* __restrict__ spill, int* __restrict__ spillcnt) {
    int si = atomicAdd(spillcnt, 1);
    if (si < SPILL_CAP) spill[si] = make_uint2(s | (q14(w) << 18), (uint)d);
}

// ---------------- pass 1: LDS-staged binning, line-coalesced flushes ----------
// bin record: word0 = src18 | dlocal9<<18 ; word1 = float weight bits
__global__ __launch_bounds__(256) void k_bin(
        const int* __restrict__ src, const int* __restrict__ dst,
        const float* __restrict__ ew, int* __restrict__ bincur,
        uint2* __restrict__ binbuf, uint2* __restrict__ spill,
        int* __restrict__ spillcnt, int E) {
    __shared__ uint2 stage[NBINS][STAGE_CAP];   // ~47 KB
    __shared__ int scnt[NBINS];
    int t = threadIdx.x;
    for (int i = t; i < NBINS; i += 256) scnt[i] = 0;
    __syncthreads();
    const int batch = 256 * EPT;
    for (int base = blockIdx.x * batch; base < E; base += gridDim.x * batch) {
        // phase A: load EPT edges up-front (independent loads), then append
        int dd[EPT]; uint ss[EPT]; float ww[EPT]; int ok[EPT];
        #pragma unroll
        for (int k = 0; k < EPT; ++k) {
            int e = base + k * 256 + t;
            ok[k] = (e < E);
            if (ok[k]) { dd[k] = dst[e]; ss[k] = (uint)src[e]; ww[k] = ew[e]; }
        }
        #pragma unroll
        for (int k = 0; k < EPT; ++k) {
            if (!ok[k]) continue;
            int bin = dd[k] >> BINSHIFT;
            int slot = atomicAdd(&scnt[bin], 1);
            if (slot < STAGE_CAP) {
                stage[bin][slot] = make_uint2(
                    ss[k] | ((uint)(dd[k] & (BINW - 1)) << 18),
                    (uint)__float_as_int(ww[k]));
            } else {
                spill_one(dd[k], ss[k], ww[k], spill, spillcnt);  // rare
            }
        }
        __syncthreads();
        // phase B: flush full chunks of 8 (64 B aligned stores)
        for (int bin = t; bin < NBINS; bin += 256) {
            int c = scnt[bin]; if (c > STAGE_CAP) c = STAGE_CAP;
            while (c >= 8) {
                int b0 = atomicAdd(&bincur[bin], 8);
                if (b0 + 8 <= BINCAP) {
                    uint4* o4 = (uint4*)(binbuf + (size_t)bin * BINCAP + b0);
                    uint2* s2 = &stage[bin][c - 8];
                    o4[0] = make_uint4(s2[0].x, s2[0].y, s2[1].x, s2[1].y);
                    o4[1] = make_uint4(s2[2].x, s2[2].y, s2[3].x, s2[3].y);
                    o4[2] = make_uint4(s2[4].x, s2[4].y, s2[5].x, s2[5].y);
                    o4[3] = make_uint4(s2[6].x, s2[6].y, s2[7].x, s2[7].y);
                } else {                                          // bin full: rare
                    for (int j = 0; j < 8; ++j) {
                        uint2 r = stage[bin][c - 8 + j];
                        spill_one((bin << BINSHIFT) + (int)(r.x >> 18),
                                  r.x & 0x3FFFFu, __int_as_float((int)r.y),
                                  spill, spillcnt);
                    }
                }
                c -= 8;
            }
            scnt[bin] = c;
        }
        __syncthreads();
    }
    // tail: drain remaining (<8 per bin) as direct partial appends
    for (int bin = t; bin < NBINS; bin += 256) {
        int c = scnt[bin]; if (c > STAGE_CAP) c = STAGE_CAP;
        if (c > 0) {
            int b0 = atomicAdd(&bincur[bin], c);
            for (int j = 0; j < c; ++j) {
                uint2 r = stage[bin][j];
                if (b0 + j < BINCAP) binbuf[(size_t)bin * BINCAP + b0 + j] = r;
                else spill_one((bin << BINSHIFT) + (int)(r.x >> 18),
                               r.x & 0x3FFFFu, __int_as_float((int)r.y),
                               spill, spillcnt);
            }
        }
    }
}

// ---------------- pass 2: per-half-bin regroup into per-dst buckets -----------
__global__ __launch_bounds__(256) void k_regroup(
        const int* __restrict__ bincur, const uint2* __restrict__ binbuf,
        uint* __restrict__ recs, int* __restrict__ cursor,
        int4* __restrict__ ovf, int* __restrict__ ovfcnt) {
    __shared__ uint image[256 * CAP];   // 47 KB, layout == recs layout
    __shared__ int cnt[256];
    int t = threadIdx.x;
    int bin  = blockIdx.x >> 1;
    int half = blockIdx.x & 1;
    cnt[t] = 0;
    __syncthreads();
    int nrec = bincur[bin]; if (nrec > BINCAP) nrec = BINCAP;
    const uint2* bb = binbuf + (size_t)bin * BINCAP;
    for (int i = t; i < nrec; i += 256) {
        uint2 r = bb[i];
        int dlocal = (int)(r.x >> 18);
        if ((dlocal >> 8) == half) {
            int dl = dlocal & 255;
            int slot = atomicAdd(&cnt[dl], 1);
            uint s = r.x & 0x3FFFFu;
            float w = __int_as_float((int)r.y);
            if (slot < CAP) {
                image[dl * CAP + slot] = (q14(w) << 18) | s;
            } else {                                            // rare high-degree
                int d = (bin << BINSHIFT) + dlocal;
                int o = atomicAdd(ovfcnt, 1);
                if (o < OVF_MAX) ovf[o] = make_int4(d, (int)s, __float_as_int(w), 0);
            }
        }
    }
    __syncthreads();
    int dbase = (bin << BINSHIFT) + half * 256;
    int ndl = NN - dbase; if (ndl > 256) ndl = 256;
    if (ndl <= 0) return;
    if (t < ndl) cursor[dbase + t] = cnt[t];    // raw count (spill adds later)
    int tot = ndl * CAP;
    uint* out = recs + (size_t)dbase * CAP;
    for (int i = t; i < tot; i += 256) out[i] = image[i];  // fully coalesced
}

// ---------------- spill fixup: old atomic path, tiny N ----------------
__global__ void k_spill_fix(const uint2* __restrict__ spill, const int* __restrict__ spillcnt,
                            uint* __restrict__ recs, int* __restrict__ cursor,
                            int4* __restrict__ ovf, int* __restrict__ ovfcnt) {
    int n = spillcnt[0]; if (n > SPILL_CAP) n = SPILL_CAP;
    for (int i = blockIdx.x * blockDim.x + threadIdx.x; i < n;
         i += gridDim.x * blockDim.x) {
        uint2 e = spill[i];
        int d = (int)e.y;
        uint s = e.x & 0x3FFFFu;
        uint q = e.x >> 18;
        int slot = atomicAdd(&cursor[d], 1);
        if (slot < CAP) recs[(size_t)d * CAP + slot] = (q << 18) | s;
        else {
            float w = (float)q * (1.0f / 16384.0f);
            int o = atomicAdd(ovfcnt, 1);
            if (o < OVF_MAX) ovf[o] = make_int4(d, (int)s, __float_as_int(w), 0);
        }
    }
}

// ---------------- fused deg + dinv from buckets (no atomics) ----------------
__global__ void k_degdinv(const int* __restrict__ cursor, const uint* __restrict__ recs,
                          float* __restrict__ deg, float* __restrict__ dinv) {
    int lane = threadIdx.x & 63;
    int n = blockIdx.x * (blockDim.x >> 6) + (threadIdx.x >> 6);
    if (n >= NN) return;
    int cnt = cursor[n]; if (cnt > CAP) cnt = CAP;
    float w = 0.0f;
    if (lane < cnt) w = (float)(recs[(size_t)n * CAP + lane] >> 18) * (1.0f / 16384.0f);
    float s = wave_reduce_add(w);
    if (lane == 0) {
        deg[n] = s;
        dinv[n] = rsqrtf(s + 1.0f);   // self-loop weight 1 folded in
    }
}

// overflow fixup: single thread, normally near-zero-trip; handles dup dsts safely
__global__ void k_ovf_fix(const int4* __restrict__ ovf, const int* __restrict__ ovfcnt,
                          float* __restrict__ deg, float* __restrict__ dinv) {
    if (threadIdx.x != 0 || blockIdx.x != 0) return;
    int n = ovfcnt[0]; if (n > OVF_MAX) n = OVF_MAX;
    for (int i = 0; i < n; ++i) {
        int d = ovf[i].x;
        float dg = deg[d] + __int_as_float(ovf[i].z);
        deg[d] = dg;
        dinv[d] = rsqrtf(dg + 1.0f);
    }
}

// ------- small GEMM + dinv row-scale, bf16 out: out[n] = bf16(dinv[n]*(row(n)@W)) --
__global__ void k_gemm(const float* __restrict__ h, const float* __restrict__ U,
                       const float* __restrict__ I, const float* __restrict__ W,
                       const float* __restrict__ dinv, ushort* __restrict__ out) {
    __shared__ float Ws[64 * 64];
    for (int i = threadIdx.x; i < 64 * 64; i += blockDim.x) Ws[i] = W[i];
    __syncthreads();
    int lane = threadIdx.x & 63;
    int wpb = blockDim.x >> 6;
    int wid = blockIdx.x * wpb + (threadIdx.x >> 6);
    int tw = gridDim.x * wpb;
    for (int n = wid; n < NN; n += tw) {
        float xv;
        if (h) xv = h[(size_t)n * D + lane];
        else   xv = (n < NU) ? U[(size_t)n * D + lane] : I[(size_t)(n - NU) * D + lane];
        float acc = 0.f;
        #pragma unroll
        for (int k = 0; k < 64; ++k)
            acc = fmaf(lane_bcast(xv, k), Ws[k * 64 + lane], acc);
        out[(size_t)n * D + lane] = f2bf(acc * dinv[n]);
    }
}

// ---------------- conv accumulate for one dst node (wave-cooperative) ---------
__device__ __forceinline__ float conv_accum(int n, int lane,
        const ushort* __restrict__ hw2b, const int* __restrict__ cursor,
        const uint* __restrict__ recs, const int4* __restrict__ ovf,
        const int* __restrict__ ovfcnt) {
    int cnt = __builtin_amdgcn_readfirstlane(cursor[n]);
    if (cnt > CAP) cnt = CAP;
    uint rv = (lane < cnt) ? recs[(size_t)n * CAP + lane] : 0u;  // coalesced bucket read
    float a = bf2f(hw2b[(size_t)n * D + lane]);                  // self-loop term
    int cp = (cnt + 7) & ~7;                                     // pad to chunk of 8
    for (int j0 = 0; j0 < cp; j0 += 8) {
        #pragma unroll
        for (int k = 0; k < 8; ++k) {
            uint r = (uint)__builtin_amdgcn_readlane((int)rv, j0 + k);  // scalar record
            int   s = (int)(r & 0x3FFFFu);
            float w = (float)(r >> 18) * (1.0f / 16384.0f);
            a = fmaf(w, bf2f(hw2b[(size_t)s * D + lane]), a);
        }
    }
    int novf = __builtin_amdgcn_readfirstlane(ovfcnt[0]);
    if (novf > 0) {                                              // normally skipped
        if (novf > OVF_MAX) novf = OVF_MAX;
        for (int j = 0; j < novf; ++j) {
            int4 e = ovf[j];
            if (e.x == n) a = fmaf(__int_as_float(e.z),
                                   bf2f(hw2b[(size_t)e.y * D + lane]), a);
        }
    }
    return a;
}

__device__ __forceinline__ float ln_relu(float v, int lane,
        const float* __restrict__ g, const float* __restrict__ be) {
    float m = wave_reduce_add(v) * (1.0f / 64.0f);
    float dv = v - m;
    float var = wave_reduce_add(dv * dv) * (1.0f / 64.0f);
    return fmaxf(dv * rsqrtf(var + 1e-5f) * g[lane] + be[lane], 0.0f);
}

// ---------------- layer-1 conv (all nodes) + bias + LN + ReLU + residual ------
__global__ __launch_bounds__(256) void k_conv1(
        const ushort* __restrict__ hw2b, const int* __restrict__ cursor,
        const uint* __restrict__ recs, const int4* __restrict__ ovf,
        const int* __restrict__ ovfcnt, const float* __restrict__ dinv,
        const float* __restrict__ b, const float* __restrict__ g,
        const float* __restrict__ be, const float* __restrict__ U,
        const float* __restrict__ I, float* __restrict__ out) {
    int lane = threadIdx.x & 63;
    int n = __builtin_amdgcn_readfirstlane(blockIdx.x * 4 + (threadIdx.x >> 6));
    if (n >= NN) return;
    float a = conv_accum(n, lane, hw2b, cursor, recs, ovf, ovfcnt);
    float v = a * dinv[n] + b[lane];
    float y = ln_relu(v, lane, g, be);
    float r = (n < NU) ? U[(size_t)n * D + lane] : I[(size_t)(n - NU) * D + lane];
    out[(size_t)n * D + lane] = y + r;
}

// ---------------- layer-2 conv ONLY for sampled nodes -------------------------
__global__ __launch_bounds__(256) void k_conv2s(
        const ushort* __restrict__ hw2b, const int* __restrict__ cursor,
        const uint* __restrict__ recs, const int4* __restrict__ ovf,
        const int* __restrict__ ovfcnt, const float* __restrict__ dinv,
        const float* __restrict__ b, const float* __restrict__ g,
        const float* __restrict__ be, const int* __restrict__ users,
        const int* __restrict__ items, const float* __restrict__ h1,
        float* __restrict__ h2s, int B) {
    int lane = threadIdx.x & 63;
    int p = blockIdx.x * 4 + (threadIdx.x >> 6);
    if (p >= 2 * B) return;
    int n = (p < B) ? users[p] : NU + items[p - B];
    n = __builtin_amdgcn_readfirstlane(n);
    float a = conv_accum(n, lane, hw2b, cursor, recs, ovf, ovfcnt);
    float v = a * dinv[n] + b[lane];
    float y = ln_relu(v, lane, g, be);
    h2s[(size_t)p * D + lane] = y + h1[(size_t)n * D + lane];
}

// ---------------- fused projection + scoring ----------------
__global__ void k_score(const float* __restrict__ h2s, const int* __restrict__ users,
                        const int* __restrict__ items, const float* __restrict__ Wp,
                        const float* __restrict__ bp, const float* __restrict__ bu,
                        const float* __restrict__ bi, const float* __restrict__ mu,
                        float* __restrict__ out, int B) {
    __shared__ float Ws[64 * 64];
    for (int i = threadIdx.x; i < 64 * 64; i += blockDim.x) Ws[i] = Wp[i];
    __syncthreads();
    int lane = threadIdx.x & 63;
    int wpb = blockDim.x >> 6;
    int wid = blockIdx.x * wpb + (threadIdx.x >> 6);
    int tw = gridDim.x * wpb;
    for (int p = wid; p < B; p += tw) {
        float hu = h2s[(size_t)p * D + lane];
        float hi = h2s[(size_t)(B + p) * D + lane];
        float pu = bp[lane], pi = bp[lane];
        #pragma unroll
        for (int k = 0; k < 64; ++k) {
            float wv = Ws[k * 64 + lane];
            pu = fmaf(lane_bcast(hu, k), wv, pu);
            pi = fmaf(lane_bcast(hi, k), wv, pi);
        }
        float s = wave_reduce_add(pu * pi);
        if (lane == 0) {
            s += bu[users[p]] + bi[items[p]] + mu[0];
            out[p] = fminf(fmaxf(s, 1.0f), 5.0f);
        }
    }
}

extern "C" void kernel_launch(void* const* d_in, const int* in_sizes, int n_in,
                              void* d_out, int out_size, void* d_ws, size_t ws_size,
                              hipStream_t stream) {
    const int*   users = (const int*)d_in[0];
    const int*   items = (const int*)d_in[1];
    const int*   ei2   = (const int*)d_in[2];
    const float* ew    = (const float*)d_in[3];
    const float* U     = (const float*)d_in[4];
    const float* I     = (const float*)d_in[5];
    const float* W0    = (const float*)d_in[6];
    const float* b0    = (const float*)d_in[7];
    const float* g0    = (const float*)d_in[8];
    const float* be0   = (const float*)d_in[9];
    const float* W1    = (const float*)d_in[10];
    const float* b1    = (const float*)d_in[11];
    const float* g1    = (const float*)d_in[12];
    const float* be1   = (const float*)d_in[13];
    const float* Wp    = (const float*)d_in[14];
    const float* bp    = (const float*)d_in[15];
    const float* bu    = (const float*)d_in[16];
    const float* bi    = (const float*)d_in[17];
    const float* mu    = (const float*)d_in[18];

    int B = in_sizes[0];
    int E = in_sizes[2] / 2;
    const int* srcp = ei2;
    const int* dstp = ei2 + E;

    // workspace carve-up (256B aligned); total ~132 MB
    char* p = (char*)d_ws;
    auto alloc = [&](size_t bytes) -> char* {
        char* r = p;
        p += (bytes + 255) & ~(size_t)255;
        return r;
    };
    float*  deg     = (float*)alloc((size_t)NN * 4);
    int*    cursor  = (int*)  alloc((size_t)NN * 4);
    float*  dinv    = (float*)alloc((size_t)NN * 4);
    int*    ovfcnt  = (int*)  alloc(256);
    int*    spillcnt= (int*)  alloc(256);
    int*    bincur  = (int*)  alloc((size_t)NBINS * 4);
    int4*   ovf     = (int4*) alloc((size_t)OVF_MAX * 16);
    uint2*  spill   = (uint2*)alloc((size_t)SPILL_CAP * 8);      // 2.1 MB
    uint2*  binbuf  = (uint2*)alloc((size_t)NBINS * BINCAP * 8); // 26.8 MB
    uint*   recs    = (uint*) alloc((size_t)NN * CAP * 4);       // 28.2 MB
    ushort* hw2b    = (ushort*)alloc((size_t)NN * D * 2);        // 19.2 MB
    float*  h1      = (float*)alloc((size_t)NN * D * 4);         // 38.4 MB
    float*  h2s     = (float*)alloc((size_t)2 * B * D * 4);      // 16.8 MB

    hipMemsetAsync(bincur, 0, (size_t)NBINS * 4, stream);
    hipMemsetAsync(spillcnt, 0, 4, stream);
    hipMemsetAsync(ovfcnt, 0, 4, stream);
    // cursor NOT memset: k_regroup writes all NN entries

    int gW = (NN + 3) / 4;          // one wave per node, 4 waves/block
    int gS = (2 * B + 3) / 4;       // one wave per sample

    // CSR build: bin -> regroup -> spill fixup
    k_bin<<<256, 256, 0, stream>>>(srcp, dstp, ew, bincur, binbuf,
                                   spill, spillcnt, E);
    k_regroup<<<NBINS * 2, 256, 0, stream>>>(bincur, binbuf, recs, cursor,
                                             ovf, ovfcnt);
    k_spill_fix<<<32, 256, 0, stream>>>(spill, spillcnt, recs, cursor,
                                        ovf, ovfcnt);
    k_degdinv<<<gW, 256, 0, stream>>>(cursor, recs, deg, dinv);
    k_ovf_fix<<<1, 64, 0, stream>>>(ovf, ovfcnt, deg, dinv);

    // layer 1 (all nodes)
    k_gemm<<<2048, 256, 0, stream>>>(nullptr, U, I, W0, dinv, hw2b);
    k_conv1<<<gW, 256, 0, stream>>>(hw2b, cursor, recs, ovf, ovfcnt, dinv,
                                    b0, g0, be0, U, I, h1);
    // layer 2 (gemm all nodes; conv only sampled nodes)
    k_gemm<<<2048, 256, 0, stream>>>(h1, U, I, W1, dinv, hw2b);
    k_conv2s<<<gS, 256, 0, stream>>>(hw2b, cursor, recs, ovf, ovfcnt, dinv,
                                     b1, g1, be1, users, items, h1, h2s, B);

    // fused projection + scoring
    k_score<<<512, 256, 0, stream>>>(h2s, users, items, Wp, bp, bu, bi, mu,
                                     (float*)d_out, B);
}